// Round 13
// baseline (203.663 us; speedup 1.0000x reference)
//
#include <hip/hip_runtime.h>

#define LENF 15
#define NZ   1e-5f

typedef float f32x2 __attribute__((ext_vector_type(2)));

__device__ __forceinline__ void uh_weights(float a, float b, float* w) {
  // gamma UH; lgamma/theta terms cancel under normalization
  float lw[LENF], m = -1e30f;
  const float ib = 1.f / b;
#pragma unroll
  for (int l = 0; l < LENF; ++l) {
    float tt = l + 0.5f;
    lw[l] = (a - 1.f) * __logf(tt) - tt * ib;
    m = fmaxf(m, lw[l]);
  }
  float s = 0.f;
#pragma unroll
  for (int l = 0; l < LENF; ++l) { w[l] = __expf(lw[l] - m); s += w[l]; }
  const float r = 1.f / s;
#pragma unroll
  for (int l = 0; l < LENF; ++l) w[l] *= r;
}

// LDS plane layout per buffer: [plane(p,t,e)][step j][lane] floats.
#define PLANE (LENF * 64)          // 960 floats
#define BUFSZ (3 * PLANE)          // 2880 floats per buffer

__global__ __launch_bounds__(64, 1) void exphydro_kernel(
    const float* __restrict__ x,      // (T, G, 3): prcp, tmean, pet
    const float* __restrict__ params, // (G, 16)
    float* __restrict__ out,          // (T, G)
    int G, int T)
{
  // 2 bufs x 3 planes x 15 steps x 64 lanes x 4B = 23040 B.
  // Staged via global_load_lds size=4 (HW-verified scatter: lane*4B).
  __shared__ float sX[2 * BUFSZ];

  const int lane = threadIdx.x;            // 0..63
  const int g    = blockIdx.x * 64 + lane;
  const int gs   = (g < G) ? g : (G - 1);  // dup lanes write identical values
                                           // to the same address: benign race

  // ---- params (+ pre-combined constants) ----
  const float* pp = params + (size_t)gs * 16;
  float P0[16];
#pragma unroll
  for (int i = 0; i < 16; ++i) P0[i] = pp[i];

  const float ddf    = P0[0]  * 40.f;
  const float Tbm    = P0[1]  * 5.f  - 2.f;
  const float wrf    = P0[2]  * 0.5f;
  const float Tbf    = P0[3]  * 7.f  - 5.f;
  const float Kf     = P0[4]  * 5.f;
  const float exp_fe = P0[5];
  const float ET_eff = P0[6];
  const float c_vad  = P0[9]  * 0.1f;
  const float c_phr  = P0[10] * (0.01f - 1e-5f) + 1e-5f;
  const float vml    = P0[11] * (500.f - 0.001f) + 0.001f;
  const float inv_vml = 1.f / vml;
  const float crp    = P0[7] * inv_vml;                             // c_run/vml
  const float cvp    = (P0[8] * (0.02f - 1e-5f) + 1e-5f) * inv_vml; // c_v2p/vml
  const float mpb    = ddf * Tbm;                                   // melt bias

  // ---- gamma UH weights, packed (w1, w2) ----
  f32x2 wv[LENF];
  {
    float w1[LENF], w2[LENF];
    uh_weights(P0[12] * (20.f - 0.3f) + 0.3f,
               P0[13] * (5.f - 0.01f) + 0.01f, w1);
    uh_weights(P0[14] * (13.f - 0.5f) + 0.5f,
               P0[15] * (1.5f - 0.15f) + 0.15f, w2);
#pragma unroll
    for (int l = 0; l < LENF; ++l) wv[l] = (f32x2){w1[l], w2[l]};
  }

  // ---- state + transposed-FIR delay line ----
  float sog = NZ, wis = NZ, vad = NZ, phr = NZ;
  f32x2 D[LENF - 1];
#pragma unroll
  for (int l = 0; l < LENF - 1; ++l) D[l] = (f32x2){0.f, 0.f};

  const unsigned Gu  = (unsigned)G;
  const size_t rowB  = (size_t)Gu * 12u;           // bytes per time step
  const char* gx     = (const char*)x + (size_t)gs * 12u;  // per-lane base
  const unsigned tmax = (unsigned)(T - 1);
  unsigned oof = (unsigned)gs;                     // running output index

  const int nc = (T + LENF - 1) / LENF;            // 73 for T=1095

  // PREP results (registers): 5 x 15 = 75 VGPRs
  float pf[LENF], mp[LENF], rp[LENF], rn[LENF], sn[LENF];

  // Issue chunk c (clamped records) into LDS buf (c&1): 45 size-4 DMAs.
  // Per-lane global source; LDS dest wave-uniform, HW scatters lane*4B.
  // ALWAYS issued (index clamps to last record), so the newest 45 VMEM ops
  // are these and vmcnt(45) below uniformly drains everything older.
#define ISSUE(c)                                                        \
  {                                                                     \
    float* ldsb_ = &sX[((c) & 1) * BUFSZ];                              \
    unsigned tb_ = (unsigned)(c) * (unsigned)LENF;                      \
    _Pragma("unroll")                                                   \
    for (int j = 0; j < LENF; ++j) {                                    \
      unsigned t_ = tb_ + (unsigned)j;                                  \
      if (t_ > tmax) t_ = tmax;                                         \
      const char* s_ = gx + (size_t)t_ * rowB;                          \
      __builtin_amdgcn_global_load_lds(                                 \
          (const __attribute__((address_space(1))) void*)s_,            \
          (__attribute__((address_space(3))) void*)(ldsb_ + 0 * PLANE + j * 64), \
          4, 0, 0);                                                     \
      __builtin_amdgcn_global_load_lds(                                 \
          (const __attribute__((address_space(1))) void*)(s_ + 4),      \
          (__attribute__((address_space(3))) void*)(ldsb_ + 1 * PLANE + j * 64), \
          4, 0, 0);                                                     \
      __builtin_amdgcn_global_load_lds(                                 \
          (const __attribute__((address_space(1))) void*)(s_ + 8),      \
          (__attribute__((address_space(3))) void*)(ldsb_ + 2 * PLANE + j * 64), \
          4, 0, 0);                                                     \
    }                                                                   \
  }

#define STEPJ(J_)                                                       \
  {                                                                     \
    float freeze = fminf(pf[J_], wis);                                  \
    wis -= freeze;                                                      \
    float sos = sog + freeze + sn[J_];                                  \
    float melt = fminf(mp[J_], sos);                                    \
    sog = sos - melt;                                                   \
    float ret = wrf * sog;                                              \
    float wtmp = wis + melt + rn[J_];                                   \
    float avail = fmaxf(wtmp - ret, 0.f);                               \
    wis = fminf(wtmp, ret);       /* == avail>0 ? ret : wtmp */         \
    float t1_ = crp * vad;                                              \
    float ht0 = t1_ * avail;                                            \
    float t2_ = cvp * vad;                                              \
    float ht1 = t2_ * vad;                                              \
    float ht2 = c_vad * vad;                                            \
    float ht3 = c_phr * phr;                                            \
    float infil = avail - ht0;                                          \
    float aet = fminf(rp[J_], vad);                                     \
    float v2_ = vad + infil - aet - ht1 - ht2;                          \
    float overflow = fmaxf(v2_ - vml, 0.f);                             \
    vad = fminf(fmaxf(v2_, NZ), vml);        /* v_med3_f32 */           \
    float qx = ht0 + overflow;                                          \
    phr = fmaxf(phr + ht1 - ht3, NZ);                                   \
    f32x2 q_; q_.x = qx; q_.y = ht2 + ht3;                              \
    f32x2 o_ = D[0] + wv[0] * q_;                                       \
    _Pragma("unroll")                                                   \
    for (int l = 0; l < LENF - 2; ++l)                                  \
      D[l] = D[l + 1] + wv[l + 1] * q_;        /* v_pk_fma_f32 */       \
    D[LENF - 2] = wv[LENF - 1] * q_;                                    \
    out[oof] = o_.x + o_.y;                                             \
    oof += Gu;                                                          \
  }

  ISSUE(0);

  for (int c = 0; c < nc; ++c) {
    ISSUE(c + 1);                       // next chunk's DMA flies over compute
                                        // (clamped dummy on the final iter)

    // Newest 45 outstanding VMEM = ISSUE(c+1). Draining to 45 retires (in
    // issue order) ISSUE(c)'s loads and all older stores -> current chunk's
    // data is in LDS. Compiler can't see the DMA->ds_read dependency, so
    // the wait is manual; sched_barrier stops hoisting past the asm.
    asm volatile("s_waitcnt vmcnt(45)" ::: "memory");
    __builtin_amdgcn_sched_barrier(0);

    const float* rowb = &sX[(c & 1) * BUFSZ + lane];

    // PREP: decode planes + transcendentals; 15 independent chains.
#pragma unroll
    for (int j = 0; j < LENF; ++j) {
      float p_  = rowb[0 * PLANE + j * 64];
      float tm_ = rowb[1 * PLANE + j * 64];
      float pe_ = rowb[2 * PLANE + j * 64];
      float rain_ = (tm_ >= 0.f) ? p_ : 0.f;
      rn[j] = rain_;
      sn[j] = p_ - rain_;
      pf[j] = Kf * __builtin_amdgcn_exp2f(
          exp_fe * __builtin_amdgcn_logf(fmaxf(Tbf - tm_, NZ)));
      mp[j] = fmaxf(ddf * tm_ - mpb, 0.f);
      rp[j] = ET_eff * pe_;
    }

    const int t0 = c * LENF;
    if (t0 + LENF <= T) {               // full chunk (all chunks at T=1095)
#pragma unroll
      for (int j = 0; j < LENF; ++j) STEPJ(j);
    } else {                            // generic partial tail
#pragma unroll
      for (int j = 0; j < LENF; ++j) if (t0 + j < T) STEPJ(j);
    }
  }

#undef ISSUE
#undef STEPJ
}

extern "C" void kernel_launch(void* const* d_in, const int* in_sizes, int n_in,
                              void* d_out, int out_size, void* d_ws, size_t ws_size,
                              hipStream_t stream) {
  const float* x      = (const float*)d_in[0];
  const float* params = (const float*)d_in[1];
  float* out          = (float*)d_out;

  int G = in_sizes[1] / 16;               // 15000
  int T = in_sizes[0] / (G * 3);          // 1095

  int block = 64;                         // 1 wave/block -> 235 waves on 235 CUs
  int grid  = (G + block - 1) / block;
  exphydro_kernel<<<grid, block, 0, stream>>>(x, params, out, G, T);
}

// Round 14
// 192.060 us; speedup vs baseline: 1.0604x; 1.0604x over previous
//
#include <hip/hip_runtime.h>

#define LENF 15
#define NZ   1e-5f
#define TT   120   // k2 time-tile (multiple of 15)

typedef float f32x2 __attribute__((ext_vector_type(2)));

struct R3 { float p, t, e; };   // 12B record -> global_load_dwordx3

__device__ __forceinline__ void uh_weights(float a, float b, float* w) {
  // gamma UH; lgamma/theta terms cancel under normalization
  float lw[LENF], m = -1e30f;
  const float ib = 1.f / b;
#pragma unroll
  for (int l = 0; l < LENF; ++l) {
    float tt = l + 0.5f;
    lw[l] = (a - 1.f) * __logf(tt) - tt * ib;
    m = fmaxf(m, lw[l]);
  }
  float s = 0.f;
#pragma unroll
  for (int l = 0; l < LENF; ++l) { w[l] = __expf(lw[l] - m); s += w[l]; }
  const float r = 1.f / s;
#pragma unroll
  for (int l = 0; l < LENF; ++l) w[l] *= r;
}

// ---------- kernel 0: per-cell UH weights -> ws (layout [l][g], f32x2) ----
__global__ __launch_bounds__(64, 1) void k_weights(
    const float* __restrict__ params, f32x2* __restrict__ wv, int G)
{
  int g = blockIdx.x * 64 + threadIdx.x;
  if (g >= G) return;
  const float* pp = params + (size_t)g * 16;
  float w1[LENF], w2[LENF];
  uh_weights(pp[12] * (20.f - 0.3f) + 0.3f, pp[13] * (5.f - 0.01f) + 0.01f, w1);
  uh_weights(pp[14] * (13.f - 0.5f) + 0.5f, pp[15] * (1.5f - 0.15f) + 0.15f, w2);
#pragma unroll
  for (int l = 0; l < LENF; ++l)
    wv[(size_t)l * G + g] = (f32x2){w1[l], w2[l]};
}

// ---------- kernel 1: serial recurrence, q=(qx,qd) packed bf16x2 ----------
__global__ __launch_bounds__(64, 1) void k_recur(
    const float* __restrict__ x,      // (T, G, 3)
    const float* __restrict__ params, // (G, 16)
    unsigned* __restrict__ qp,        // (T+14, G) rows 0..13 are zero pad
    int G, int T)
{
  int g = blockIdx.x * 64 + threadIdx.x;
  const int gs = (g < G) ? g : (G - 1);   // dup lanes: benign same-value store

  const float* pp = params + (size_t)gs * 16;
  const float ddf    = pp[0]  * 40.f;
  const float Tbm    = pp[1]  * 5.f  - 2.f;
  const float wrf    = pp[2]  * 0.5f;
  const float Tbf    = pp[3]  * 7.f  - 5.f;
  const float Kf     = pp[4]  * 5.f;
  const float exp_fe = pp[5];
  const float ET_eff = pp[6];
  const float c_vad  = pp[9]  * 0.1f;
  const float c_phr  = pp[10] * (0.01f - 1e-5f) + 1e-5f;
  const float vml    = pp[11] * (500.f - 0.001f) + 0.001f;
  const float inv_vml = 1.f / vml;
  const float crp    = pp[7] * inv_vml;                             // c_run/vml
  const float cvp    = (pp[8] * (0.02f - 1e-5f) + 1e-5f) * inv_vml; // c_v2p/vml
  const float mpb    = ddf * Tbm;
  const float omcp   = 1.f - c_phr;

  float sog = NZ, wis = NZ, vad = NZ, phr = NZ;

  const unsigned Gu = (unsigned)G;
  const R3* xg = (const R3*)x + gs;       // record idx = t*G + gs (<2^31 B)
  unsigned oof = 14u * Gu + (unsigned)gs; // q row = t + 14

  R3 A[LENF], B[LENF];
  float px[LENF], snmp[LENF], pf[LENF], rp[LENF];
  const int nb = T / LENF;                // 73, exact at T=1095

#define LOAD(BUF, blk)                                                \
  {                                                                   \
    unsigned b0_ = (unsigned)(blk) * (unsigned)LENF * Gu;             \
    _Pragma("unroll")                                                 \
    for (int j = 0; j < LENF; ++j) BUF[j] = xg[b0_ + (unsigned)j * Gu]; \
  }

  // input-only: p, snow - melt_pot, pot_freeze, ret_pot
#define PREP(BUF)                                                     \
  {                                                                   \
    _Pragma("unroll")                                                 \
    for (int j = 0; j < LENF; ++j) {                                  \
      float p_ = BUF[j].p, tm_ = BUF[j].t;                            \
      float rain_ = (tm_ >= 0.f) ? p_ : 0.f;                          \
      float mp_ = fmaxf(ddf * tm_ - mpb, 0.f);                        \
      px[j]   = p_;                                                   \
      snmp[j] = (p_ - rain_) - mp_;                                   \
      pf[j]   = Kf * __builtin_amdgcn_exp2f(                          \
          exp_fe * __builtin_amdgcn_logf(fmaxf(Tbf - tm_, NZ)));      \
      rp[j]   = ET_eff * BUF[j].e;                                    \
    }                                                                 \
  }

  // Shortened-chain step (verified identities):
  //  sog2 = max(sog + freeze + snow - mp, 0)
  //  wtmp = wis + sog + p - sog2
  //  v2   = K1 + avail - C*avail,  K1 = vad - aet - (cvp*vad + c_vad)*vad
#define STEPJ(J_)                                                     \
  {                                                                   \
    float freeze = fminf(pf[J_], wis);                                \
    float sg_ = sog + snmp[J_];                                       \
    float sog2 = fmaxf(sg_ + freeze, 0.f);                            \
    float base = (wis + sog) + px[J_];                                \
    float wtmp = base - sog2;                                         \
    float ret = wrf * sog2;                                           \
    float avail = fmaxf(wtmp - ret, 0.f);                             \
    wis = fminf(wtmp, ret);                                           \
    sog = sog2;                                                       \
    float t2v = cvp * vad;                                            \
    float u_  = t2v + c_vad;                                          \
    float h12 = u_ * vad;                                             \
    float aet = fminf(rp[J_], vad);                                   \
    float K1 = (vad - aet) - h12;                                     \
    float C  = crp * vad;                                             \
    float ht1 = t2v * vad;                                            \
    float ht2 = c_vad * vad;                                          \
    float tv = K1 + avail;                                            \
    float v2 = fmaf(-C, avail, tv);                                   \
    float overflow = fmaxf(v2 - vml, 0.f);                            \
    vad = fminf(fmaxf(v2, NZ), vml);         /* v_med3 */             \
    float qx = fmaf(C, avail, overflow);                              \
    float qd = fmaf(c_phr, phr, ht2);                                 \
    phr = fmaxf(fmaf(phr, omcp, ht1), NZ);                            \
    unsigned pk_;                                                     \
    asm("v_cvt_pk_bf16_f32 %0, %1, %2" : "=v"(pk_) : "v"(qx), "v"(qd)); \
    qp[oof] = pk_;                                                    \
    oof += Gu;                                                        \
  }

#define BLOCKC(BUF)                                                   \
  {                                                                   \
    PREP(BUF);                                                        \
    _Pragma("unroll")                                                 \
    for (int j = 0; j < LENF; ++j) STEPJ(j);                          \
  }

  LOAD(A, 0);
  int k = 0;
  while (k + 2 <= nb) {
    LOAD(B, k + 1);
    BLOCKC(A);
    if (k + 2 < nb) LOAD(A, k + 2);
    BLOCKC(B);
    k += 2;
  }
  if (k < nb) { BLOCKC(A); }
  // generic tail (empty at T=1095)
  for (int t = nb * LENF; t < T; ++t) {
    R3 r = xg[(unsigned)t * Gu];
    float rain_ = (r.t >= 0.f) ? r.p : 0.f;
    px[0] = r.p;
    snmp[0] = (r.p - rain_) - fmaxf(ddf * r.t - mpb, 0.f);
    pf[0] = Kf * __builtin_amdgcn_exp2f(
        exp_fe * __builtin_amdgcn_logf(fmaxf(Tbf - r.t, NZ)));
    rp[0] = ET_eff * r.e;
    STEPJ(0);
  }
#undef LOAD
#undef PREP
#undef STEPJ
#undef BLOCKC
}

// ---------- kernel 2: parallel 15-tap conv over padded q ------------------
__global__ __launch_bounds__(256, 2) void k_conv(
    const unsigned* __restrict__ qp,   // (T+14, G) bf16x2-packed
    const f32x2* __restrict__ wv,      // [l][g]
    float* __restrict__ out,           // (T, G)
    int G, int T)
{
  const int g  = blockIdx.x * 256 + threadIdx.x;
  const int gs = (g < G) ? g : (G - 1);
  const int t0 = blockIdx.y * TT;
  const int steps = min(TT, T - t0);
  const int nch = steps / LENF;            // exact (T, TT multiples of 15)
  const unsigned Gu = (unsigned)G;

  f32x2 w[LENF];
#pragma unroll
  for (int l = 0; l < LENF; ++l) w[l] = wv[(size_t)l * Gu + gs];

  const unsigned* qb = qp + (size_t)t0 * Gu + gs;  // row r = time t0-14+r

  f32x2 r[LENF];
#pragma unroll
  for (int j = 0; j < LENF - 1; ++j) {     // preload q[t0-14 .. t0-1]
    unsigned u = qb[(size_t)j * Gu];
    r[j].x = __uint_as_float(u << 16);
    r[j].y = __uint_as_float(u & 0xFFFF0000u);
  }

  float* ob = out + (size_t)t0 * Gu + gs;
  const bool valid = (g < G);

  for (int cc = 0; cc < nch; ++cc) {
    const size_t rb = (size_t)(cc * LENF + 14) * Gu;
#pragma unroll
    for (int m = 0; m < LENF; ++m) {
      // insert q[t0+cc*15+m] into slot (m+14)%15 (static index)
      const int slot = (m + 14) % LENF;
      unsigned u = qb[rb + (size_t)m * Gu];
      r[slot].x = __uint_as_float(u << 16);
      r[slot].y = __uint_as_float(u & 0xFFFF0000u);
      f32x2 acc = (f32x2){0.f, 0.f};
#pragma unroll
      for (int l = 0; l < LENF; ++l) {
        const int s = (m + 14 - l + LENF) % LENF;   // static
        acc += w[l] * r[s];
      }
      if (valid) ob[(size_t)(cc * LENF + m) * Gu] = acc.x + acc.y;
    }
  }
}

// ---------- fallback: R8 fused kernel (known-good, 149.5 us) --------------
__global__ __launch_bounds__(64, 1) void exphydro_fused(
    const float* __restrict__ x, const float* __restrict__ params,
    float* __restrict__ out, int G, int T)
{
  int g = blockIdx.x * 64 + threadIdx.x;
  if (g >= G) return;
  const float* pp = params + (size_t)g * 16;
  float P0[16];
#pragma unroll
  for (int i = 0; i < 16; ++i) P0[i] = pp[i];
  const float ddf    = P0[0]  * 40.f;
  const float Tbm    = P0[1]  * 5.f  - 2.f;
  const float wrf    = P0[2]  * 0.5f;
  const float Tbf    = P0[3]  * 7.f  - 5.f;
  const float Kf     = P0[4]  * 5.f;
  const float exp_fe = P0[5];
  const float ET_eff = P0[6];
  const float c_vad  = P0[9]  * 0.1f;
  const float c_phr  = P0[10] * (0.01f - 1e-5f) + 1e-5f;
  const float vml    = P0[11] * (500.f - 0.001f) + 0.001f;
  const float inv_vml = 1.f / vml;
  const float crp    = P0[7] * inv_vml;
  const float cvp    = (P0[8] * (0.02f - 1e-5f) + 1e-5f) * inv_vml;
  const float mpb    = ddf * Tbm;
  f32x2 wv[LENF];
  {
    float w1[LENF], w2[LENF];
    uh_weights(P0[12] * (20.f - 0.3f) + 0.3f, P0[13] * (5.f - 0.01f) + 0.01f, w1);
    uh_weights(P0[14] * (13.f - 0.5f) + 0.5f, P0[15] * (1.5f - 0.15f) + 0.15f, w2);
#pragma unroll
    for (int l = 0; l < LENF; ++l) wv[l] = (f32x2){w1[l], w2[l]};
  }
  float sog = NZ, wis = NZ, vad = NZ, phr = NZ;
  f32x2 D[LENF - 1];
#pragma unroll
  for (int l = 0; l < LENF - 1; ++l) D[l] = (f32x2){0.f, 0.f};
  const unsigned Gu = (unsigned)G;
  const R3* xg = (const R3*)x + g;
  unsigned oof = (unsigned)g;
  R3 A[LENF], B[LENF];
  float pf[LENF], mp[LENF], rp[LENF];
  const int nb = T / LENF;
#define LOADF(BUF, blk)                                               \
  { unsigned b0_ = (unsigned)(blk) * (unsigned)LENF * Gu;             \
    _Pragma("unroll")                                                 \
    for (int j = 0; j < LENF; ++j) BUF[j] = xg[b0_ + (unsigned)j * Gu]; }
#define PREPF(BUF)                                                    \
  { _Pragma("unroll")                                                 \
    for (int j = 0; j < LENF; ++j) {                                  \
      float tm_ = BUF[j].t;                                           \
      pf[j] = Kf * __builtin_amdgcn_exp2f(                            \
          exp_fe * __builtin_amdgcn_logf(fmaxf(Tbf - tm_, NZ)));      \
      mp[j] = fmaxf(ddf * tm_ - mpb, 0.f);                            \
      rp[j] = ET_eff * BUF[j].e; } }
#define STEPF(BUF, J_)                                                \
  { float p_ = BUF[J_].p, tm_ = BUF[J_].t;                            \
    float rain = (tm_ >= 0.f) ? p_ : 0.f;                             \
    float snow = p_ - rain;                                           \
    float freeze = fminf(pf[J_], wis);                                \
    wis -= freeze;                                                    \
    float sos = sog + freeze + snow;                                  \
    float melt = fminf(mp[J_], sos);                                  \
    sog = sos - melt;                                                 \
    float ret = wrf * sog;                                            \
    float wtmp = wis + melt + rain;                                   \
    float avail = fmaxf(wtmp - ret, 0.f);                             \
    wis = fminf(wtmp, ret);                                           \
    float t1_ = crp * vad;                                            \
    float ht0 = t1_ * avail;                                          \
    float t2_ = cvp * vad;                                            \
    float ht1 = t2_ * vad;                                            \
    float ht2 = c_vad * vad;                                          \
    float ht3 = c_phr * phr;                                          \
    float infil = avail - ht0;                                        \
    float aet = fminf(rp[J_], vad);                                   \
    float v2_ = vad + infil - aet - ht1 - ht2;                        \
    float overflow = fmaxf(v2_ - vml, 0.f);                           \
    vad = fminf(fmaxf(v2_, NZ), vml);                                 \
    float qx = ht0 + overflow;                                        \
    phr = fmaxf(phr + ht1 - ht3, NZ);                                 \
    f32x2 q_; q_.x = qx; q_.y = ht2 + ht3;                            \
    f32x2 o_ = D[0] + wv[0] * q_;                                     \
    _Pragma("unroll")                                                 \
    for (int l = 0; l < LENF - 2; ++l)                                \
      D[l] = D[l + 1] + wv[l + 1] * q_;                               \
    D[LENF - 2] = wv[LENF - 1] * q_;                                  \
    out[oof] = o_.x + o_.y;                                           \
    oof += Gu; }
  LOADF(A, 0);
  int k = 0;
  while (k + 2 <= nb) {
    LOADF(B, k + 1);
    PREPF(A);
#pragma unroll
    for (int j = 0; j < LENF; ++j) STEPF(A, j);
    if (k + 2 < nb) LOADF(A, k + 2);
    PREPF(B);
#pragma unroll
    for (int j = 0; j < LENF; ++j) STEPF(B, j);
    k += 2;
  }
  if (k < nb) {
    PREPF(A);
#pragma unroll
    for (int j = 0; j < LENF; ++j) STEPF(A, j);
  }
#undef LOADF
#undef PREPF
#undef STEPF
}

extern "C" void kernel_launch(void* const* d_in, const int* in_sizes, int n_in,
                              void* d_out, int out_size, void* d_ws, size_t ws_size,
                              hipStream_t stream) {
  const float* x      = (const float*)d_in[0];
  const float* params = (const float*)d_in[1];
  float* out          = (float*)d_out;

  int G = in_sizes[1] / 16;               // 15000
  int T = in_sizes[0] / (G * 3);          // 1095

  size_t qBytes = (size_t)(T + 14) * G * 4;
  size_t wBytes = (size_t)G * LENF * 8;

  if (ws_size >= qBytes + wBytes && (T % LENF) == 0) {
    unsigned* qp = (unsigned*)d_ws;
    f32x2*    wv = (f32x2*)((char*)d_ws + qBytes);
    hipMemsetAsync(d_ws, 0, (size_t)14 * G * 4, stream);   // zero pad rows
    int grid64 = (G + 63) / 64;
    k_weights<<<grid64, 64, 0, stream>>>(params, wv, G);
    k_recur<<<grid64, 64, 0, stream>>>(x, params, qp, G, T);
    dim3 g2((G + 255) / 256, (T + TT - 1) / TT);
    k_conv<<<g2, 256, 0, stream>>>(qp, wv, out, G, T);
  } else {
    int grid64 = (G + 63) / 64;
    exphydro_fused<<<grid64, 64, 0, stream>>>(x, params, out, G, T);
  }
}

// Round 15
// 148.545 us; speedup vs baseline: 1.3711x; 1.2929x over previous
//
#include <hip/hip_runtime.h>

#define LENF 15
#define NZ   1e-5f

typedef float f32x2 __attribute__((ext_vector_type(2)));

struct R3 { float p, t, e; };   // 12B record -> global_load_dwordx3

__device__ __forceinline__ void uh_weights(float a, float b, float* w) {
  // gamma UH; lgamma/theta terms cancel under normalization
  float lw[LENF], m = -1e30f;
  const float ib = 1.f / b;
#pragma unroll
  for (int l = 0; l < LENF; ++l) {
    float tt = l + 0.5f;
    lw[l] = (a - 1.f) * __logf(tt) - tt * ib;
    m = fmaxf(m, lw[l]);
  }
  float s = 0.f;
#pragma unroll
  for (int l = 0; l < LENF; ++l) { w[l] = __expf(lw[l] - m); s += w[l]; }
  const float r = 1.f / s;
#pragma unroll
  for (int l = 0; l < LENF; ++l) w[l] *= r;
}

__global__ __launch_bounds__(64, 1) void exphydro_kernel(
    const float* __restrict__ x,      // (T, G, 3): prcp, tmean, pet
    const float* __restrict__ params, // (G, 16)
    float* __restrict__ out,          // (T, G)
    int G, int T)
{
  int g = blockIdx.x * 64 + threadIdx.x;
  if (g >= G) return;

  // ---- params (+ pre-combined constants) ----
  const float* pp = params + (size_t)g * 16;
  float P0[16];
#pragma unroll
  for (int i = 0; i < 16; ++i) P0[i] = pp[i];

  const float ddf    = P0[0]  * 40.f;
  const float Tbm    = P0[1]  * 5.f  - 2.f;
  const float wrf    = P0[2]  * 0.5f;
  const float Tbf    = P0[3]  * 7.f  - 5.f;
  const float Kf     = P0[4]  * 5.f;
  const float exp_fe = P0[5];
  const float ET_eff = P0[6];
  const float c_vad  = P0[9]  * 0.1f;
  const float c_phr  = P0[10] * (0.01f - 1e-5f) + 1e-5f;
  const float vml    = P0[11] * (500.f - 0.001f) + 0.001f;
  const float inv_vml = 1.f / vml;
  const float crp    = P0[7] * inv_vml;                             // c_run/vml
  const float cvp    = (P0[8] * (0.02f - 1e-5f) + 1e-5f) * inv_vml; // c_v2p/vml
  const float mpb    = ddf * Tbm;                                   // melt bias
  const float omcp   = 1.f - c_phr;

  // ---- gamma UH weights, packed (w1, w2) ----
  f32x2 wv[LENF];
  {
    float w1[LENF], w2[LENF];
    uh_weights(P0[12] * (20.f - 0.3f) + 0.3f,
               P0[13] * (5.f - 0.01f) + 0.01f, w1);
    uh_weights(P0[14] * (13.f - 0.5f) + 0.5f,
               P0[15] * (1.5f - 0.15f) + 0.15f, w2);
#pragma unroll
    for (int l = 0; l < LENF; ++l) wv[l] = (f32x2){w1[l], w2[l]};
  }

  // ---- state + transposed-FIR delay line ----
  float sog = NZ, wis = NZ, vad = NZ, phr = NZ;
  f32x2 D[LENF - 1];
#pragma unroll
  for (int l = 0; l < LENF - 1; ++l) D[l] = (f32x2){0.f, 0.f};

  const unsigned Gu = (unsigned)G;
  const R3* xg = (const R3*)x + g;     // record idx = t*G + g (<2^31 bytes)
  unsigned oof = (unsigned)g;          // running output index

  R3 A[LENF], B[LENF];
  float snmp[LENF], pf[LENF], rp[LENF];   // PREP results
  const int nb = T / LENF;                // 73 full blocks at T=1095

#define LOAD(BUF, blk)                                                \
  {                                                                   \
    unsigned b0_ = (unsigned)(blk) * (unsigned)LENF * Gu;             \
    _Pragma("unroll")                                                 \
    for (int j = 0; j < LENF; ++j) BUF[j] = xg[b0_ + (unsigned)j * Gu]; \
  }

  // input-only precompute: snow-melt_pot, pot_freeze, ret_pot
#define PREP(BUF)                                                     \
  {                                                                   \
    _Pragma("unroll")                                                 \
    for (int j = 0; j < LENF; ++j) {                                  \
      float p_ = BUF[j].p, tm_ = BUF[j].t;                            \
      float rain_ = (tm_ >= 0.f) ? p_ : 0.f;                          \
      float mp_ = fmaxf(ddf * tm_ - mpb, 0.f);                        \
      snmp[j] = (p_ - rain_) - mp_;                                   \
      pf[j]   = Kf * __builtin_amdgcn_exp2f(                          \
          exp_fe * __builtin_amdgcn_logf(fmaxf(Tbf - tm_, NZ)));      \
      rp[j]   = ET_eff * BUF[j].e;                                    \
    }                                                                 \
  }

  // Shortened-chain step (identities verified vs reference, R14 passed):
  //  sog2 = max(sog + freeze + snow - mp, 0)
  //  wtmp = (wis + sog) + p - sog2
  //  v2   = K1 + avail - C*avail, K1 = (vad - aet) - (cvp*vad + c_vad)*vad
  //  phr' = max(fma(phr, 1-c_phr, ht1), NZ)
#define STEPJ(BUF, J_)                                                \
  {                                                                   \
    float freeze = fminf(pf[J_], wis);                                \
    float sg_ = sog + snmp[J_];                                       \
    float sog2 = fmaxf(sg_ + freeze, 0.f);                            \
    float base = (wis + sog) + BUF[J_].p;                             \
    float wtmp = base - sog2;                                         \
    float ret = wrf * sog2;                                           \
    float avail = fmaxf(wtmp - ret, 0.f);                             \
    wis = fminf(wtmp, ret);                                           \
    sog = sog2;                                                       \
    float t2v = cvp * vad;                                            \
    float u_  = t2v + c_vad;                                          \
    float h12 = u_ * vad;                                             \
    float aet = fminf(rp[J_], vad);                                   \
    float K1 = (vad - aet) - h12;                                     \
    float C  = crp * vad;                                             \
    float ht1 = t2v * vad;                                            \
    float ht2 = c_vad * vad;                                          \
    float tv = K1 + avail;                                            \
    float v2 = fmaf(-C, avail, tv);                                   \
    float overflow = fmaxf(v2 - vml, 0.f);                            \
    vad = fminf(fmaxf(v2, NZ), vml);         /* v_med3 */             \
    float qx = fmaf(C, avail, overflow);                              \
    float qd = fmaf(c_phr, phr, ht2);                                 \
    phr = fmaxf(fmaf(phr, omcp, ht1), NZ);                            \
    f32x2 q_; q_.x = qx; q_.y = qd;                                   \
    f32x2 o_ = D[0] + wv[0] * q_;                                     \
    _Pragma("unroll")                                                 \
    for (int l = 0; l < LENF - 2; ++l)                                \
      D[l] = D[l + 1] + wv[l + 1] * q_;        /* v_pk_fma_f32 */     \
    D[LENF - 2] = wv[LENF - 1] * q_;                                  \
    out[oof] = o_.x + o_.y;                                           \
    oof += Gu;                                                        \
  }

#define BLOCKC(BUF)                                                   \
  {                                                                   \
    PREP(BUF);                                                        \
    _Pragma("unroll")                                                 \
    for (int j = 0; j < LENF; ++j) STEPJ(BUF, j);                     \
  }

  LOAD(A, 0);
  int k = 0;
  while (k + 2 <= nb) {
    LOAD(B, k + 1);                 // next block's loads fly over PREP+steps
    BLOCKC(A);
    if (k + 2 < nb) LOAD(A, k + 2);
    BLOCKC(B);
    k += 2;
  }
  if (k < nb) { BLOCKC(A); }
  // generic guarded tail (empty at T=1095)
  for (int t = nb * LENF; t < T; ++t) {
    A[0] = xg[(unsigned)t * Gu];
    float p_ = A[0].p, tm_ = A[0].t;
    float rain_ = (tm_ >= 0.f) ? p_ : 0.f;
    snmp[0] = (p_ - rain_) - fmaxf(ddf * tm_ - mpb, 0.f);
    pf[0] = Kf * __builtin_amdgcn_exp2f(
        exp_fe * __builtin_amdgcn_logf(fmaxf(Tbf - tm_, NZ)));
    rp[0] = ET_eff * A[0].e;
    STEPJ(A, 0);
  }

#undef LOAD
#undef PREP
#undef STEPJ
#undef BLOCKC
}

extern "C" void kernel_launch(void* const* d_in, const int* in_sizes, int n_in,
                              void* d_out, int out_size, void* d_ws, size_t ws_size,
                              hipStream_t stream) {
  const float* x      = (const float*)d_in[0];
  const float* params = (const float*)d_in[1];
  float* out          = (float*)d_out;

  int G = in_sizes[1] / 16;               // 15000
  int T = in_sizes[0] / (G * 3);          // 1095

  int block = 64;                         // 1 wave/block -> 235 waves on 235 SIMDs
  int grid  = (G + block - 1) / block;
  exphydro_kernel<<<grid, block, 0, stream>>>(x, params, out, G, T);
}

// Round 16
// 147.079 us; speedup vs baseline: 1.3847x; 1.0100x over previous
//
#include <hip/hip_runtime.h>

#define LENF 15
#define NZ   1e-5f

typedef float f32x2 __attribute__((ext_vector_type(2)));

struct R3 { float p, t, e; };   // 12B record -> global_load_dwordx3

__device__ __forceinline__ void uh_weights(float a, float b, float* w) {
  // gamma UH; lgamma/theta terms cancel under normalization
  float lw[LENF], m = -1e30f;
  const float ib = 1.f / b;
#pragma unroll
  for (int l = 0; l < LENF; ++l) {
    float tt = l + 0.5f;
    lw[l] = (a - 1.f) * __logf(tt) - tt * ib;
    m = fmaxf(m, lw[l]);
  }
  float s = 0.f;
#pragma unroll
  for (int l = 0; l < LENF; ++l) { w[l] = __expf(lw[l] - m); s += w[l]; }
  const float r = 1.f / s;
#pragma unroll
  for (int l = 0; l < LENF; ++l) w[l] *= r;
}

__global__ __launch_bounds__(64, 1) void exphydro_kernel(
    const float* __restrict__ x,      // (T, G, 3): prcp, tmean, pet
    const float* __restrict__ params, // (G, 16)
    float* __restrict__ out,          // (T, G)
    int G, int T)
{
  int g = blockIdx.x * 64 + threadIdx.x;
  if (g >= G) return;

  // ---- params (+ pre-combined constants) ----
  const float* pp = params + (size_t)g * 16;
  float P0[16];
#pragma unroll
  for (int i = 0; i < 16; ++i) P0[i] = pp[i];

  const float ddf    = P0[0]  * 40.f;
  const float Tbm    = P0[1]  * 5.f  - 2.f;
  const float wrf    = P0[2]  * 0.5f;
  const float Tbf    = P0[3]  * 7.f  - 5.f;
  const float Kf     = P0[4]  * 5.f;
  const float exp_fe = P0[5];
  const float ET_eff = P0[6];
  const float c_vad  = P0[9]  * 0.1f;
  const float c_phr  = P0[10] * (0.01f - 1e-5f) + 1e-5f;
  const float vml    = P0[11] * (500.f - 0.001f) + 0.001f;
  const float inv_vml = 1.f / vml;
  const float crp    = P0[7] * inv_vml;                             // c_run/vml
  const float cvp    = (P0[8] * (0.02f - 1e-5f) + 1e-5f) * inv_vml; // c_v2p/vml
  const float mpb    = ddf * Tbm;                                   // melt bias
  const float omcp   = 1.f - c_phr;

  // ---- gamma UH weights, packed (w1, w2) ----
  f32x2 wv[LENF];
  {
    float w1[LENF], w2[LENF];
    uh_weights(P0[12] * (20.f - 0.3f) + 0.3f,
               P0[13] * (5.f - 0.01f) + 0.01f, w1);
    uh_weights(P0[14] * (13.f - 0.5f) + 0.5f,
               P0[15] * (1.5f - 0.15f) + 0.15f, w2);
#pragma unroll
    for (int l = 0; l < LENF; ++l) wv[l] = (f32x2){w1[l], w2[l]};
  }

  // ---- state + transposed-FIR delay line ----
  float sog = NZ, wis = NZ, vad = NZ, phr = NZ;
  f32x2 D[LENF - 1];
#pragma unroll
  for (int l = 0; l < LENF - 1; ++l) D[l] = (f32x2){0.f, 0.f};

  const unsigned Gu = (unsigned)G;
  const R3* xg = (const R3*)x + g;     // record idx = t*G + g (<2^31 bytes)
  unsigned oof = (unsigned)g;          // running output index

  R3 A[LENF], B[LENF];
  float snmp[LENF], pf[LENF], rp[LENF];   // PREP results
  const int nb = T / LENF;                // 73 full blocks at T=1095

  // LOAD + FENCE: the empty memory-clobber asm pins the load issue point
  // (compiler cannot sink VMEM past it), forcing a TRUE register double
  // buffer: loads fly ~15 steps (~4800 cyc) before their uses. No waitcnt
  // is generated at the fence itself (no data dependency).
#define LOAD(BUF, blk)                                                \
  {                                                                   \
    unsigned b0_ = (unsigned)(blk) * (unsigned)LENF * Gu;             \
    _Pragma("unroll")                                                 \
    for (int j = 0; j < LENF; ++j) BUF[j] = xg[b0_ + (unsigned)j * Gu]; \
    asm volatile("" ::: "memory");                                    \
  }

  // input-only precompute: snow-melt_pot, pot_freeze, ret_pot
#define PREP(BUF)                                                     \
  {                                                                   \
    _Pragma("unroll")                                                 \
    for (int j = 0; j < LENF; ++j) {                                  \
      float p_ = BUF[j].p, tm_ = BUF[j].t;                            \
      float rain_ = (tm_ >= 0.f) ? p_ : 0.f;                          \
      float mp_ = fmaxf(ddf * tm_ - mpb, 0.f);                        \
      snmp[j] = (p_ - rain_) - mp_;                                   \
      pf[j]   = Kf * __builtin_amdgcn_exp2f(                          \
          exp_fe * __builtin_amdgcn_logf(fmaxf(Tbf - tm_, NZ)));      \
      rp[j]   = ET_eff * BUF[j].e;                                    \
    }                                                                 \
  }

  // Shortened-chain step (identities verified vs reference, R14/R15 passed)
#define STEPJ(BUF, J_)                                                \
  {                                                                   \
    float freeze = fminf(pf[J_], wis);                                \
    float sg_ = sog + snmp[J_];                                       \
    float sog2 = fmaxf(sg_ + freeze, 0.f);                            \
    float base = (wis + sog) + BUF[J_].p;                             \
    float wtmp = base - sog2;                                         \
    float ret = wrf * sog2;                                           \
    float avail = fmaxf(wtmp - ret, 0.f);                             \
    wis = fminf(wtmp, ret);                                           \
    sog = sog2;                                                       \
    float t2v = cvp * vad;                                            \
    float u_  = t2v + c_vad;                                          \
    float h12 = u_ * vad;                                             \
    float aet = fminf(rp[J_], vad);                                   \
    float K1 = (vad - aet) - h12;                                     \
    float C  = crp * vad;                                             \
    float ht1 = t2v * vad;                                            \
    float ht2 = c_vad * vad;                                          \
    float tv = K1 + avail;                                            \
    float v2 = fmaf(-C, avail, tv);                                   \
    float overflow = fmaxf(v2 - vml, 0.f);                            \
    vad = fminf(fmaxf(v2, NZ), vml);         /* v_med3 */             \
    float qx = fmaf(C, avail, overflow);                              \
    float qd = fmaf(c_phr, phr, ht2);                                 \
    phr = fmaxf(fmaf(phr, omcp, ht1), NZ);                            \
    f32x2 q_; q_.x = qx; q_.y = qd;                                   \
    f32x2 o_ = D[0] + wv[0] * q_;                                     \
    _Pragma("unroll")                                                 \
    for (int l = 0; l < LENF - 2; ++l)                                \
      D[l] = D[l + 1] + wv[l + 1] * q_;        /* v_pk_fma_f32 */     \
    D[LENF - 2] = wv[LENF - 1] * q_;                                  \
    out[oof] = o_.x + o_.y;                                           \
    oof += Gu;                                                        \
  }

#define BLOCKC(BUF)                                                   \
  {                                                                   \
    PREP(BUF);                                                        \
    _Pragma("unroll")                                                 \
    for (int j = 0; j < LENF; ++j) STEPJ(BUF, j);                     \
  }

  LOAD(A, 0);
  int k = 0;
  while (k + 2 <= nb) {
    LOAD(B, k + 1);                 // pinned: issues before BLOCKC(A)
    BLOCKC(A);
    if (k + 2 < nb) LOAD(A, k + 2);
    BLOCKC(B);
    k += 2;
  }
  if (k < nb) { BLOCKC(A); }
  // generic guarded tail (empty at T=1095)
  for (int t = nb * LENF; t < T; ++t) {
    A[0] = xg[(unsigned)t * Gu];
    float p_ = A[0].p, tm_ = A[0].t;
    float rain_ = (tm_ >= 0.f) ? p_ : 0.f;
    snmp[0] = (p_ - rain_) - fmaxf(ddf * tm_ - mpb, 0.f);
    pf[0] = Kf * __builtin_amdgcn_exp2f(
        exp_fe * __builtin_amdgcn_logf(fmaxf(Tbf - tm_, NZ)));
    rp[0] = ET_eff * A[0].e;
    STEPJ(A, 0);
  }

#undef LOAD
#undef PREP
#undef STEPJ
#undef BLOCKC
}

extern "C" void kernel_launch(void* const* d_in, const int* in_sizes, int n_in,
                              void* d_out, int out_size, void* d_ws, size_t ws_size,
                              hipStream_t stream) {
  const float* x      = (const float*)d_in[0];
  const float* params = (const float*)d_in[1];
  float* out          = (float*)d_out;

  int G = in_sizes[1] / 16;               // 15000
  int T = in_sizes[0] / (G * 3);          // 1095

  int block = 64;                         // 1 wave/block -> 235 waves on 235 SIMDs
  int grid  = (G + block - 1) / block;
  exphydro_kernel<<<grid, block, 0, stream>>>(x, params, out, G, T);
}